// Round 1
// baseline (350.223 us; speedup 1.0000x reference)
//
#include <hip/hip_runtime.h>

#define NC 2048      // N_CLASSES
#define NB 65536     // BATCH

// ---------------- reduction helpers ----------------

__device__ inline float wred_sum(float v) {
#pragma unroll
    for (int o = 32; o > 0; o >>= 1) v += __shfl_xor(v, o);
    return v;
}

__device__ inline float wred_max(float v) {
#pragma unroll
    for (int o = 32; o > 0; o >>= 1) v = fmaxf(v, __shfl_xor(v, o));
    return v;
}

__device__ inline float bred_sum(float v) {
    __shared__ float sm[4];
    v = wred_sum(v);
    __syncthreads();
    if ((threadIdx.x & 63) == 0) sm[threadIdx.x >> 6] = v;
    __syncthreads();
    return sm[0] + sm[1] + sm[2] + sm[3];
}

__device__ inline float bred_max(float v) {
    __shared__ float sm[4];
    v = wred_max(v);
    __syncthreads();
    if ((threadIdx.x & 63) == 0) sm[threadIdx.x >> 6] = v;
    __syncthreads();
    return fmaxf(fmaxf(sm[0], sm[1]), fmaxf(sm[2], sm[3]));
}

// ---------------- transpose H -> HT (2048x2048 f32) ----------------

__global__ __launch_bounds__(256) void hcl_transpose(const float* __restrict__ H,
                                                     float* __restrict__ HT) {
    __shared__ float tile[32][33];
    const int bx = blockIdx.x * 32, by = blockIdx.y * 32;
    const int tx = threadIdx.x, ty = threadIdx.y;  // 32 x 8
#pragma unroll
    for (int i = 0; i < 32; i += 8)
        tile[ty + i][tx] = H[(size_t)(by + ty + i) * NC + bx + tx];
    __syncthreads();
#pragma unroll
    for (int i = 0; i < 32; i += 8)
        HT[(size_t)(bx + ty + i) * NC + by + tx] = tile[tx][ty + i];
}

// ---------------- main per-row kernel ----------------
// MODE 0: HT available, write per-row partials
// MODE 1: no HT (strided column reads), write partials
// MODE 2: no HT, atomic accumulate into out (out must be zeroed first)

template <int MODE>
__global__ __launch_bounds__(256) void hcl_row_kernel(
    const float* __restrict__ logits, const int* __restrict__ targets,
    const float* __restrict__ H, const float* __restrict__ HT,
    float* __restrict__ partial, float* __restrict__ out) {
    const int row = blockIdx.x;
    const int tid = threadIdx.x;

    const float4* lrow = (const float4*)(logits + (size_t)row * NC);
    float4 a = lrow[tid];
    float4 b = lrow[tid + 256];
    const int t = targets[row];

    // ---- max over row ----
    float m8 = fmaxf(fmaxf(fmaxf(a.x, a.y), fmaxf(a.z, a.w)),
                     fmaxf(fmaxf(b.x, b.y), fmaxf(b.z, b.w)));
    float m = bred_max(m8);

    // ---- stash x_t (logit at target) ----
    __shared__ float sXt;
    if (t < 1024) {
        if (tid == (t >> 2)) sXt = ((const float*)&a)[t & 3];
    } else {
        if (tid == ((t - 1024) >> 2)) sXt = ((const float*)&b)[t & 3];
    }
    // (visibility of sXt guaranteed by the __syncthreads inside bred_sum below)

    // ---- unnormalized probs ----
    float ea0 = __expf(a.x - m), ea1 = __expf(a.y - m), ea2 = __expf(a.z - m), ea3 = __expf(a.w - m);
    float eb0 = __expf(b.x - m), eb1 = __expf(b.y - m), eb2 = __expf(b.z - m), eb3 = __expf(b.w - m);
    float z = ea0 + ea1 + ea2 + ea3 + eb0 + eb1 + eb2 + eb3;

    // ---- child: row t of H (coalesced) ----
    const float4* hr = (const float4*)(H + (size_t)t * NC);
    float4 ha = hr[tid], hb = hr[tid + 256];
    float cs = ea0 * ha.x + ea1 * ha.y + ea2 * ha.z + ea3 * ha.w +
               eb0 * hb.x + eb1 * hb.y + eb2 * hb.z + eb3 * hb.w;
    float hcs = ha.x + ha.y + ha.z + ha.w + hb.x + hb.y + hb.z + hb.w;

    // ---- parent: column t of H ----
    float ps, hps;
    if (MODE == 0) {
        const float4* pr = (const float4*)(HT + (size_t)t * NC);
        float4 pa = pr[tid], pb = pr[tid + 256];
        ps = ea0 * pa.x + ea1 * pa.y + ea2 * pa.z + ea3 * pa.w +
             eb0 * pb.x + eb1 * pb.y + eb2 * pb.z + eb3 * pb.w;
        hps = pa.x + pa.y + pa.z + pa.w + pb.x + pb.y + pb.z + pb.w;
    } else {
        ps = 0.f; hps = 0.f;
        int g0 = 4 * tid;
        float e0[4] = {ea0, ea1, ea2, ea3};
        float e1[4] = {eb0, eb1, eb2, eb3};
#pragma unroll
        for (int k = 0; k < 4; k++) {
            float hv = H[(size_t)(g0 + k) * NC + t];
            ps += e0[k] * hv; hps += hv;
        }
        int g1 = 1024 + 4 * tid;
#pragma unroll
        for (int k = 0; k < 4; k++) {
            float hv = H[(size_t)(g1 + k) * NC + t];
            ps += e1[k] * hv; hps += hv;
        }
    }

    // ---- block reductions ----
    float Z   = bred_sum(z);
    float CS  = bred_sum(cs);
    float HCS = bred_sum(hcs);
    float PS  = bred_sum(ps);
    float HPS = bred_sum(hps);

    if (tid == 0) {
        float xt = sXt;
        float pt = __expf(xt - m) / Z;
        float ce = logf(Z) + (m - xt);        // -log p_t
        float psn = PS / Z, csn = CS / Z;
        float h = 0.f;
        if (HPS > 0.f) h += fmaxf(pt - psn, 0.f);
        if (HCS > 0.f) h += fmaxf(csn - pt, 0.f);
        float val = ce + h;                   // ALPHA = 1
        if (MODE == 2) {
            atomicAdd(out, val * (1.0f / NB));
        } else {
            partial[row] = val;
        }
    }
}

// ---------------- final reduction of per-row partials ----------------

__global__ __launch_bounds__(1024) void hcl_final(const float* __restrict__ partial,
                                                  float* __restrict__ out) {
    __shared__ double sm[16];
    double acc = 0.0;
    for (int i = threadIdx.x; i < NB; i += 1024) acc += (double)partial[i];
#pragma unroll
    for (int o = 32; o > 0; o >>= 1) acc += __shfl_xor(acc, o);
    const int wid = threadIdx.x >> 6, lane = threadIdx.x & 63;
    if (lane == 0) sm[wid] = acc;
    __syncthreads();
    if (threadIdx.x == 0) {
        double s = 0.0;
        for (int i = 0; i < 16; i++) s += sm[i];
        out[0] = (float)(s / (double)NB);
    }
}

// ---------------- launch ----------------

extern "C" void kernel_launch(void* const* d_in, const int* in_sizes, int n_in,
                              void* d_out, int out_size, void* d_ws, size_t ws_size,
                              hipStream_t stream) {
    const float* logits  = (const float*)d_in[0];
    const int*   targets = (const int*)d_in[1];
    const float* H       = (const float*)d_in[2];
    float* out = (float*)d_out;

    const size_t HT_FLOATS = (size_t)NC * NC;           // 4 Mi floats = 16 MB
    const size_t NEED_FULL = (HT_FLOATS + NB) * sizeof(float);
    const size_t NEED_PART = (size_t)NB * sizeof(float);

    if (ws_size >= NEED_FULL) {
        float* HT = (float*)d_ws;
        float* partial = HT + HT_FLOATS;
        hcl_transpose<<<dim3(64, 64), dim3(32, 8), 0, stream>>>(H, HT);
        hcl_row_kernel<0><<<NB, 256, 0, stream>>>(logits, targets, H, HT, partial, out);
        hcl_final<<<1, 1024, 0, stream>>>(partial, out);
    } else if (ws_size >= NEED_PART) {
        float* partial = (float*)d_ws;
        hcl_row_kernel<1><<<NB, 256, 0, stream>>>(logits, targets, H, nullptr, partial, out);
        hcl_final<<<1, 1024, 0, stream>>>(partial, out);
    } else {
        hipMemsetAsync(d_out, 0, sizeof(float), stream);
        hcl_row_kernel<2><<<NB, 256, 0, stream>>>(logits, targets, H, nullptr, nullptr, out);
    }
}

// Round 2
// 133.670 us; speedup vs baseline: 2.6201x; 2.6201x over previous
//
#include <hip/hip_runtime.h>

#define NC 2048      // N_CLASSES
#define NB 65536     // BATCH
#define CAP 64       // max parents/children per class on the fast path

// ---------------- reduction helpers ----------------

__device__ inline float wred_sum(float v) {
#pragma unroll
    for (int o = 32; o > 0; o >>= 1) v += __shfl_xor(v, o);
    return v;
}

__device__ inline float wred_max(float v) {
#pragma unroll
    for (int o = 32; o > 0; o >>= 1) v = fmaxf(v, __shfl_xor(v, o));
    return v;
}

__device__ inline float bred_sum(float v) {
    __shared__ float sm[4];
    v = wred_sum(v);
    __syncthreads();
    if ((threadIdx.x & 63) == 0) sm[threadIdx.x >> 6] = v;
    __syncthreads();
    return sm[0] + sm[1] + sm[2] + sm[3];
}

__device__ inline float bred_max(float v) {
    __shared__ float sm[4];
    v = wred_max(v);
    __syncthreads();
    if ((threadIdx.x & 63) == 0) sm[threadIdx.x >> 6] = v;
    __syncthreads();
    return fmaxf(fmaxf(sm[0], sm[1]), fmaxf(sm[2], sm[3]));
}

// ---------------- transpose H -> HT (2048x2048 f32) ----------------

__global__ __launch_bounds__(256) void hcl_transpose(const float* __restrict__ H,
                                                     float* __restrict__ HT) {
    __shared__ float tile[32][33];
    const int bx = blockIdx.x * 32, by = blockIdx.y * 32;
    const int tx = threadIdx.x, ty = threadIdx.y;  // 32 x 8
#pragma unroll
    for (int i = 0; i < 32; i += 8)
        tile[ty + i][tx] = H[(size_t)(by + ty + i) * NC + bx + tx];
    __syncthreads();
#pragma unroll
    for (int i = 0; i < 32; i += 8)
        HT[(size_t)(bx + ty + i) * NC + by + tx] = tile[tx][ty + i];
}

// ---------------- build per-class index lists (deterministic ballot compaction) ----
// One wave per row of M: idx[row*CAP + k] = k-th nonzero column (ascending),
// cnt[row] = exact nonzero count (may exceed CAP; entries beyond CAP dropped).

__global__ __launch_bounds__(256) void hcl_build(const float* __restrict__ M,
                                                 int* __restrict__ cnt,
                                                 int* __restrict__ idx) {
    const int row  = blockIdx.x * 4 + (threadIdx.x >> 6);
    const int lane = threadIdx.x & 63;
    int count = 0;
#pragma unroll
    for (int k = 0; k < NC / 64; ++k) {
        const int c = k * 64 + lane;
        const float v = M[(size_t)row * NC + c];
        const unsigned long long mask = __ballot(v != 0.0f);
        if (v != 0.0f) {
            const int pos = count + __popcll(mask & ((1ull << lane) - 1ull));
            if (pos < CAP) idx[row * CAP + pos] = c;
        }
        count += __popcll(mask);
    }
    if (lane == 0) cnt[row] = count;
}

// ---------------- main per-row kernel (sparse gather path) ----------------

__device__ inline void hcl_finalize(float xt, float m, float Z, float PS, float CS,
                                    int cp, int cc, float* __restrict__ partial, int row) {
    const float pt  = __expf(xt - m) / Z;
    const float ce  = logf(Z) + (m - xt);   // -log p_t
    float h = 0.f;
    if (cp > 0) h += fmaxf(pt - PS / Z, 0.f);
    if (cc > 0) h += fmaxf(CS / Z - pt, 0.f);
    partial[row] = ce + h;                   // ALPHA = 1
}

__global__ __launch_bounds__(256) void hcl_row2(
    const float* __restrict__ logits, const int* __restrict__ targets,
    const float* __restrict__ H, const float* __restrict__ HT,
    const int* __restrict__ pcnt, const int* __restrict__ ccnt,
    const int* __restrict__ pidx, const int* __restrict__ cidx,
    float* __restrict__ partial) {
    __shared__ float4 sExp4[512];
    const int row = blockIdx.x;
    const int tid = threadIdx.x;

    const float4* lrow = (const float4*)(logits + (size_t)row * NC);
    float4 a = lrow[tid];
    float4 b = lrow[tid + 256];
    const int t = targets[row];

    float m8 = fmaxf(fmaxf(fmaxf(a.x, a.y), fmaxf(a.z, a.w)),
                     fmaxf(fmaxf(b.x, b.y), fmaxf(b.z, b.w)));
    const float m = bred_max(m8);

    float4 ea, eb;
    ea.x = __expf(a.x - m); ea.y = __expf(a.y - m); ea.z = __expf(a.z - m); ea.w = __expf(a.w - m);
    eb.x = __expf(b.x - m); eb.y = __expf(b.y - m); eb.z = __expf(b.z - m); eb.w = __expf(b.w - m);
    sExp4[tid] = ea;            // linear layout: sExp[c] = exp(x_c - m)
    sExp4[tid + 256] = eb;
    float z = ea.x + ea.y + ea.z + ea.w + eb.x + eb.y + eb.z + eb.w;
    const float Z = bred_sum(z);   // internal syncs also publish sExp4

    const int cp = pcnt[t], cc = ccnt[t];
    const float* sExp = (const float*)sExp4;

    if (cp <= CAP && cc <= CAP) {
        if (tid < 64) {
            float vp = (tid < cp) ? sExp[pidx[t * CAP + tid]] : 0.f;
            float vc = (tid < cc) ? sExp[cidx[t * CAP + tid]] : 0.f;
            vp = wred_sum(vp);
            vc = wred_sum(vc);
            if (tid == 0) {
                const float xt = logits[(size_t)row * NC + t];  // L1 hit
                hcl_finalize(xt, m, Z, vp, vc, cp, cc, partial, row);
            }
        }
    } else {
        // dense fallback (never taken for this data; correctness safety net)
        const float4* hr = (const float4*)(H + (size_t)t * NC);
        const float4* pr = (const float4*)(HT + (size_t)t * NC);
        float4 ha = hr[tid], hb = hr[tid + 256];
        float4 pa = pr[tid], pb = pr[tid + 256];
        float cs = ea.x * ha.x + ea.y * ha.y + ea.z * ha.z + ea.w * ha.w +
                   eb.x * hb.x + eb.y * hb.y + eb.z * hb.z + eb.w * hb.w;
        float ps = ea.x * pa.x + ea.y * pa.y + ea.z * pa.z + ea.w * pa.w +
                   eb.x * pb.x + eb.y * pb.y + eb.z * pb.z + eb.w * pb.w;
        const float PS = bred_sum(ps);
        const float CS = bred_sum(cs);
        if (tid == 0) {
            const float xt = logits[(size_t)row * NC + t];
            hcl_finalize(xt, m, Z, PS, CS, cp, cc, partial, row);
        }
    }
}

// ---------------- legacy fallback row kernel (small-ws paths) ----------------

template <int MODE>  // 1: strided column, write partials; 2: atomic into out
__global__ __launch_bounds__(256) void hcl_row_kernel(
    const float* __restrict__ logits, const int* __restrict__ targets,
    const float* __restrict__ H, float* __restrict__ partial, float* __restrict__ out) {
    const int row = blockIdx.x;
    const int tid = threadIdx.x;

    const float4* lrow = (const float4*)(logits + (size_t)row * NC);
    float4 a = lrow[tid];
    float4 b = lrow[tid + 256];
    const int t = targets[row];

    float m8 = fmaxf(fmaxf(fmaxf(a.x, a.y), fmaxf(a.z, a.w)),
                     fmaxf(fmaxf(b.x, b.y), fmaxf(b.z, b.w)));
    float m = bred_max(m8);

    float ea0 = __expf(a.x - m), ea1 = __expf(a.y - m), ea2 = __expf(a.z - m), ea3 = __expf(a.w - m);
    float eb0 = __expf(b.x - m), eb1 = __expf(b.y - m), eb2 = __expf(b.z - m), eb3 = __expf(b.w - m);
    float z = ea0 + ea1 + ea2 + ea3 + eb0 + eb1 + eb2 + eb3;

    const float4* hr = (const float4*)(H + (size_t)t * NC);
    float4 ha = hr[tid], hb = hr[tid + 256];
    float cs = ea0 * ha.x + ea1 * ha.y + ea2 * ha.z + ea3 * ha.w +
               eb0 * hb.x + eb1 * hb.y + eb2 * hb.z + eb3 * hb.w;
    float hcs = ha.x + ha.y + ha.z + ha.w + hb.x + hb.y + hb.z + hb.w;

    float ps = 0.f, hps = 0.f;
    float e0[4] = {ea0, ea1, ea2, ea3};
    float e1[4] = {eb0, eb1, eb2, eb3};
    int g0 = 4 * tid;
#pragma unroll
    for (int k = 0; k < 4; k++) {
        float hv = H[(size_t)(g0 + k) * NC + t];
        ps += e0[k] * hv; hps += hv;
    }
    int g1 = 1024 + 4 * tid;
#pragma unroll
    for (int k = 0; k < 4; k++) {
        float hv = H[(size_t)(g1 + k) * NC + t];
        ps += e1[k] * hv; hps += hv;
    }

    float Z   = bred_sum(z);
    float CS  = bred_sum(cs);
    float HCS = bred_sum(hcs);
    float PS  = bred_sum(ps);
    float HPS = bred_sum(hps);

    if (tid == 0) {
        __shared__ float dummy; (void)dummy;
        float xt = logits[(size_t)row * NC + t];
        float pt = __expf(xt - m) / Z;
        float ce = logf(Z) + (m - xt);
        float h = 0.f;
        if (HPS > 0.f) h += fmaxf(pt - PS / Z, 0.f);
        if (HCS > 0.f) h += fmaxf(CS / Z - pt, 0.f);
        float val = ce + h;
        if (MODE == 2) atomicAdd(out, val * (1.0f / NB));
        else           partial[row] = val;
    }
}

// ---------------- final reduction (two deterministic stages) ----------------

__global__ __launch_bounds__(1024) void hcl_final1(const float* __restrict__ partial,
                                                   double* __restrict__ partial2) {
    __shared__ double sm[16];
    double acc = (double)partial[blockIdx.x * 1024 + threadIdx.x];
#pragma unroll
    for (int o = 32; o > 0; o >>= 1) acc += __shfl_xor(acc, o);
    const int wid = threadIdx.x >> 6, lane = threadIdx.x & 63;
    if (lane == 0) sm[wid] = acc;
    __syncthreads();
    if (threadIdx.x == 0) {
        double s = 0.0;
#pragma unroll
        for (int i = 0; i < 16; i++) s += sm[i];
        partial2[blockIdx.x] = s;
    }
}

__global__ __launch_bounds__(64) void hcl_final2(const double* __restrict__ partial2,
                                                 float* __restrict__ out) {
    double acc = partial2[threadIdx.x];
#pragma unroll
    for (int o = 32; o > 0; o >>= 1) acc += __shfl_xor(acc, o);
    if (threadIdx.x == 0) out[0] = (float)(acc / (double)NB);
}

__global__ __launch_bounds__(1024) void hcl_final_single(const float* __restrict__ partial,
                                                         float* __restrict__ out) {
    __shared__ double sm[16];
    double acc = 0.0;
    for (int i = threadIdx.x; i < NB; i += 1024) acc += (double)partial[i];
#pragma unroll
    for (int o = 32; o > 0; o >>= 1) acc += __shfl_xor(acc, o);
    const int wid = threadIdx.x >> 6, lane = threadIdx.x & 63;
    if (lane == 0) sm[wid] = acc;
    __syncthreads();
    if (threadIdx.x == 0) {
        double s = 0.0;
        for (int i = 0; i < 16; i++) s += sm[i];
        out[0] = (float)(s / (double)NB);
    }
}

// ---------------- launch ----------------

extern "C" void kernel_launch(void* const* d_in, const int* in_sizes, int n_in,
                              void* d_out, int out_size, void* d_ws, size_t ws_size,
                              hipStream_t stream) {
    const float* logits  = (const float*)d_in[0];
    const int*   targets = (const int*)d_in[1];
    const float* H       = (const float*)d_in[2];
    float* out = (float*)d_out;

    // fast-path workspace layout
    const size_t HT_F   = (size_t)NC * NC;          // 16 MB
    const size_t PART_F = (size_t)NB;               // 256 KB
    size_t off = 0;
    float*  HT       = (float*)d_ws;                 off += HT_F * 4;
    float*  partial  = (float*)((char*)d_ws + off);  off += PART_F * 4;
    double* partial2 = (double*)((char*)d_ws + off); off += 64 * 8;
    int*    pcnt     = (int*)((char*)d_ws + off);    off += NC * 4;
    int*    ccnt     = (int*)((char*)d_ws + off);    off += NC * 4;
    int*    pidx     = (int*)((char*)d_ws + off);    off += (size_t)NC * CAP * 4;
    int*    cidx     = (int*)((char*)d_ws + off);    off += (size_t)NC * CAP * 4;
    const size_t NEED_FAST = off;
    const size_t NEED_PART = (size_t)NB * sizeof(float);

    if (ws_size >= NEED_FAST) {
        hcl_transpose<<<dim3(64, 64), dim3(32, 8), 0, stream>>>(H, HT);
        hcl_build<<<NC / 4, 256, 0, stream>>>(H,  ccnt, cidx);   // children(r) = nonzero cols of row r
        hcl_build<<<NC / 4, 256, 0, stream>>>(HT, pcnt, pidx);   // parents(c)  = nonzero rows of col c
        hcl_row2<<<NB, 256, 0, stream>>>(logits, targets, H, HT, pcnt, ccnt, pidx, cidx, partial);
        hcl_final1<<<64, 1024, 0, stream>>>(partial, partial2);
        hcl_final2<<<1, 64, 0, stream>>>(partial2, out);
    } else if (ws_size >= NEED_PART) {
        float* part = (float*)d_ws;
        hcl_row_kernel<1><<<NB, 256, 0, stream>>>(logits, targets, H, part, out);
        hcl_final_single<<<1, 1024, 0, stream>>>(part, out);
    } else {
        hipMemsetAsync(d_out, 0, sizeof(float), stream);
        hcl_row_kernel<2><<<NB, 256, 0, stream>>>(logits, targets, H, nullptr, out);
    }
}